// Round 8
// baseline (396.455 us; speedup 1.0000x reference)
//
#include <hip/hip_runtime.h>

// GAT layer, N=6144, IN_F=256, OUT_F=64, HEADS=4.
// Outputs: out [6144,256] f32 then attn [4,6144,6144] f32 (concatenated in d_out).
//
//  K0 k_prep : split x and W^T into bf16 hi/lo pairs (double-bf16 GEMM inputs).
//  K1 k_h    : h = x@W via 3x MFMA -> h_t bf16 [head][o][n]; fused attn_src/attn_dst
//              reductions -> srcL/dstL (pre-scaled by log2 e).
//  K2 k_maxd : per-head global max of dstL (leaky monotone -> analytic softmax max bound).
//  K3 k_sums : ONE adj pass, all 4 heads at once (wave per row): row sums ->
//              ccL[h][r] = -log2(s) - mL  (or -inf for empty rows).
//  K4 k_attn5: ALL 4 HEADS IN ONE BLOCK (1024 thr / 16 waves; wave = (head, j-quarter),
//              16-row tiles). Evidence: per-head blocks gave FETCH = 4x adj (708 MB) --
//              no L3 reuse across head-blocks (different XCDs + nt stream flushes L3).
//              One block -> adj tile read ONCE from HBM, 4 head-waves hit same-XCD L2.
//              Store path stays ROUND-2-VERIFIED: LDS repack + fences + full-line
//              NONTEMPORAL stores (round 7 proved plain cached stores are 90us WORSE:
//              L2/L3 thrash). A-frag direct from registers. No launch_bounds reg cap
//              (round 6 proved VGPR=40 strangulation costs 2x).

#define NNODE 6144
#define INFEAT 256
#define OUTF 64
#define NHEAD 4
#define L2E 1.4426950408889634f

typedef short bf16x8 __attribute__((ext_vector_type(8)));
typedef float f32x4 __attribute__((ext_vector_type(4)));
typedef int   i32x4 __attribute__((ext_vector_type(4)));
typedef unsigned short u16x4 __attribute__((ext_vector_type(4)));

__device__ __forceinline__ unsigned short f2b(float f) {
  unsigned u = __builtin_bit_cast(unsigned, f);
  unsigned r = u + 0x7FFFu + ((u >> 16) & 1u);
  return (unsigned short)(r >> 16);
}
__device__ __forceinline__ float b2f(unsigned short b) {
  unsigned u = ((unsigned)b) << 16;
  return __builtin_bit_cast(float, u);
}
__device__ __forceinline__ float leaky(float t) {
  return fmaxf(t, 0.f) + 0.2f * fminf(t, 0.f);
}
__device__ __forceinline__ void lds_fence() {
  asm volatile("s_waitcnt lgkmcnt(0)" ::: "memory");
  __builtin_amdgcn_sched_barrier(0);
}

// ---------------- K0: prep ----------------
__global__ __launch_bounds__(256) void k_prep(
    const float* __restrict__ x, const float* __restrict__ W,
    unsigned short* __restrict__ x_hi, unsigned short* __restrict__ x_lo,
    unsigned short* __restrict__ wt_hi, unsigned short* __restrict__ wt_lo) {
  const int tid = blockIdx.x * 256 + threadIdx.x;
  const int nth = gridDim.x * 256;
  for (int i = tid; i < NNODE * INFEAT; i += nth) {
    float f = x[i];
    unsigned short h = f2b(f);
    x_hi[i] = h;
    x_lo[i] = f2b(f - b2f(h));
  }
  for (int i = tid; i < NHEAD * INFEAT * OUTF; i += nth) {
    const int head = i / (INFEAT * OUTF);
    const int rem = i % (INFEAT * OUTF);
    const int k = rem / OUTF, o = rem % OUTF;
    float f = W[i];
    const int dst = (head * OUTF + o) * INFEAT + k;
    unsigned short h = f2b(f);
    wt_hi[dst] = h;
    wt_lo[dst] = f2b(f - b2f(h));
  }
}

// ---------------- K1: h = x@W (double-bf16 MFMA) + attn_src/dst ----------------
__global__ __launch_bounds__(256) void k_h(
    const unsigned short* __restrict__ x_hi, const unsigned short* __restrict__ x_lo,
    const unsigned short* __restrict__ wt_hi, const unsigned short* __restrict__ wt_lo,
    const float* __restrict__ a_src, const float* __restrict__ a_dst,
    unsigned short* __restrict__ h_t, float* __restrict__ srcL, float* __restrict__ dstL) {
  const int n0 = blockIdx.x * 16;
  const int head = threadIdx.x >> 6;
  const int lane = threadIdx.x & 63;
  const int q = lane >> 4, l15 = lane & 15;

  f32x4 acc[4];
#pragma unroll
  for (int nt = 0; nt < 4; ++nt)
#pragma unroll
    for (int e = 0; e < 4; ++e) acc[nt][e] = 0.f;

  const unsigned short* xh = x_hi + (size_t)(n0 + l15) * INFEAT + q * 8;
  const unsigned short* xl = x_lo + (size_t)(n0 + l15) * INFEAT + q * 8;

#pragma unroll
  for (int ks = 0; ks < INFEAT / 32; ++ks) {
    bf16x8 ah = *(const bf16x8*)(xh + ks * 32);
    bf16x8 al = *(const bf16x8*)(xl + ks * 32);
#pragma unroll
    for (int nt = 0; nt < 4; ++nt) {
      const size_t boff = (size_t)(head * OUTF + nt * 16 + l15) * INFEAT + ks * 32 + q * 8;
      bf16x8 bh = *(const bf16x8*)(wt_hi + boff);
      bf16x8 bl = *(const bf16x8*)(wt_lo + boff);
      acc[nt] = __builtin_amdgcn_mfma_f32_16x16x32_bf16(ah, bh, acc[nt], 0, 0, 0);
      acc[nt] = __builtin_amdgcn_mfma_f32_16x16x32_bf16(al, bh, acc[nt], 0, 0, 0);
      acc[nt] = __builtin_amdgcn_mfma_f32_16x16x32_bf16(ah, bl, acc[nt], 0, 0, 0);
    }
  }

  float ps[4] = {0.f, 0.f, 0.f, 0.f}, pd[4] = {0.f, 0.f, 0.f, 0.f};
#pragma unroll
  for (int nt = 0; nt < 4; ++nt) {
    const int o = nt * 16 + l15;
    const float av = a_src[head * OUTF + o];
    const float dv = a_dst[head * OUTF + o];
    unsigned short pk[4];
#pragma unroll
    for (int e = 0; e < 4; ++e) {
      float v = acc[nt][e];
      ps[e] += v * av;
      pd[e] += v * dv;
      pk[e] = f2b(v);
    }
    u16x4 pv = {pk[0], pk[1], pk[2], pk[3]};
    *(u16x4*)(h_t + (size_t)(head * OUTF + o) * NNODE + n0 + q * 4) = pv;
  }
#pragma unroll
  for (int e = 0; e < 4; ++e) {
#pragma unroll
    for (int msk = 1; msk <= 8; msk <<= 1) {
      ps[e] += __shfl_xor(ps[e], msk);
      pd[e] += __shfl_xor(pd[e], msk);
    }
  }
  if (l15 == 0) {
    const int n = n0 + q * 4;
    f32x4 s4 = {ps[0] * L2E, ps[1] * L2E, ps[2] * L2E, ps[3] * L2E};
    f32x4 d4 = {pd[0] * L2E, pd[1] * L2E, pd[2] * L2E, pd[3] * L2E};
    *(f32x4*)(srcL + head * NNODE + n) = s4;
    *(f32x4*)(dstL + head * NNODE + n) = d4;
  }
}

// ---------------- K2: per-head global max of dstL ----------------
__global__ __launch_bounds__(256) void k_maxd(const float* __restrict__ dstL,
                                              float* __restrict__ maxdL) {
  const int head = blockIdx.x;
  const int t = threadIdx.x;
  float m = -INFINITY;
  for (int n = t; n < NNODE; n += 256) m = fmaxf(m, dstL[head * NNODE + n]);
#pragma unroll
  for (int msk = 1; msk <= 32; msk <<= 1) m = fmaxf(m, __shfl_xor(m, msk));
  __shared__ float red[4];
  if ((t & 63) == 0) red[t >> 6] = m;
  __syncthreads();
  if (t == 0) maxdL[head] = fmaxf(fmaxf(red[0], red[1]), fmaxf(red[2], red[3]));
}

// ---------------- K3: one adj pass, all heads: ccL[h][r] = -log2(s)-mL ----------------
__global__ __launch_bounds__(256) void k_sums(
    const int* __restrict__ adj, const float* __restrict__ srcL,
    const float* __restrict__ dstL, const float* __restrict__ maxdL,
    float* __restrict__ ccL) {
  const int r = blockIdx.x * 4 + (threadIdx.x >> 6);  // wave per row
  const int lane = threadIdx.x & 63;
  float sl[NHEAD], mL[NHEAD], s[NHEAD];
#pragma unroll
  for (int h = 0; h < NHEAD; ++h) {
    sl[h] = srcL[h * NNODE + r];
    mL[h] = leaky(sl[h] + maxdL[h]);
    s[h] = 0.f;
  }
  const int* arow = adj + (size_t)r * NNODE;
  for (int j = lane * 4; j < NNODE; j += 256) {
    i32x4 a = *(const i32x4*)(arow + j);
#pragma unroll
    for (int h = 0; h < NHEAD; ++h) {
      f32x4 d = *(const f32x4*)(dstL + h * NNODE + j);
#pragma unroll
      for (int e = 0; e < 4; ++e) {
        float t = sl[h] + d[e];
        float lr = fmaxf(t, 0.f) + 0.2f * fminf(t, 0.f);
        s[h] += a[e] ? __builtin_exp2f(lr - mL[h]) : 0.f;
      }
    }
  }
#pragma unroll
  for (int h = 0; h < NHEAD; ++h) {
#pragma unroll
    for (int msk = 1; msk <= 32; msk <<= 1) s[h] += __shfl_xor(s[h], msk);
  }
  if (lane == 0) {
#pragma unroll
    for (int h = 0; h < NHEAD; ++h)
      ccL[h * NNODE + r] = (s[h] > 0.f) ? (-__builtin_log2f(s[h]) - mL[h]) : -INFINITY;
  }
}

// ---------------- K4: 4 heads/block, 16 waves, nt full-line stores + MFMA PV ----------
__global__ __launch_bounds__(1024) void k_attn5(
    const int* __restrict__ adj, const float* __restrict__ srcL,
    const float* __restrict__ ccL, const float* __restrict__ dstL,
    const unsigned short* __restrict__ h_t,
    float* __restrict__ out, float* __restrict__ attn) {
  // union: 16 wave-private repack buffers (16 x 16 rows x 36 floats = 9216 floats)
  //        | epilogue cbuf [2][4][16][64] (8192 floats)
  __shared__ float smem_f[9216];  // 36 KB

  const int i0 = blockIdx.x * 16;  // 16-row tile, shared by all 4 heads
  const int w = threadIdx.x >> 6;
  const int head = w >> 2;   // wave's head
  const int jq = w & 3;      // wave's j-quarter
  const int lane = threadIdx.x & 63;
  const int q = lane >> 4, l15 = lane & 15;
  const int r0 = i0 + l15;

  const float sl0 = srcL[head * NNODE + r0];
  const float cc0 = ccL[head * NNODE + r0];  // -log2(sum) - mL  (-inf if empty row)
  const float* dptr = dstL + head * NNODE;
  float* pb = smem_f + w * 576;  // 16 x 36 floats, wave-private

  f32x4 acc[4];
#pragma unroll
  for (int nt = 0; nt < 4; ++nt)
#pragma unroll
    for (int e = 0; e < 4; ++e) acc[nt][e] = 0.f;

  float* attnH = attn + (size_t)head * NNODE * NNODE;
  const unsigned short* hb = h_t + (size_t)head * OUTF * NNODE;
  const int jb = jq * (NNODE / 4);
  const int jend = jb + (NNODE / 4);

  for (int jc = jb; jc < jend; jc += 32) {
    const int j0 = jc + q * 8;
    // adj tile read once per block from HBM; 4 head-waves hit same-XCD L2
    f32x4 d0 = *(const f32x4*)(dptr + j0);
    f32x4 d1 = *(const f32x4*)(dptr + j0 + 4);
    i32x4 a00 = *(const i32x4*)(adj + (size_t)r0 * NNODE + j0);
    i32x4 a01 = *(const i32x4*)(adj + (size_t)r0 * NNODE + j0 + 4);
    float p0v[8];
#pragma unroll
    for (int e = 0; e < 8; ++e) {
      const float de = (e < 4) ? d0[e & 3] : d1[e & 3];
      const int ae0 = (e < 4) ? a00[e & 3] : a01[e & 3];
      float t0 = sl0 + de;
      float lr0 = fmaxf(t0, 0.f) + 0.2f * fminf(t0, 0.f);
      p0v[e] = ae0 ? __builtin_exp2f(lr0 + cc0) : 0.f;
    }

    // ---- repack through wave-private LDS, then full-line nt stores ----
    {
      f32x4 q00 = {p0v[0], p0v[1], p0v[2], p0v[3]};
      f32x4 q01 = {p0v[4], p0v[5], p0v[6], p0v[7]};
      *(f32x4*)&pb[l15 * 36 + q * 8] = q00;
      *(f32x4*)&pb[l15 * 36 + q * 8 + 4] = q01;
    }
    lds_fence();  // writes visible to all lanes of this wave
#pragma unroll
    for (int t = 0; t < 2; ++t) {
      const int rr = t * 8 + (lane >> 3);
      const int c = (lane & 7) * 4;
      f32x4 v = *(const f32x4*)&pb[rr * 36 + c];
      // 64 lanes cover 8 rows x 128B each: every 64B line fully written
      __builtin_nontemporal_store(v, (f32x4*)(attnH + (size_t)(i0 + rr) * NNODE + jc + c));
    }
    lds_fence();  // reads retired before next iteration's writes

    // ---- PV MFMA (A-frag direct from registers, round-2-verified layout) ----
    bf16x8 af0;
#pragma unroll
    for (int e = 0; e < 8; ++e) af0[e] = (short)f2b(p0v[e]);
#pragma unroll
    for (int nt = 0; nt < 4; ++nt) {
      bf16x8 bf = *(const bf16x8*)(hb + (size_t)(nt * 16 + l15) * NNODE + j0);
      acc[nt] = __builtin_amdgcn_mfma_f32_16x16x32_bf16(af0, bf, acc[nt], 0, 0, 0);
    }
  }

  // -------- epilogue: combine the 4 j-quarter waves per head --------
  __syncthreads();  // pbuf -> cbuf aliasing: all waves done with pbuf
  float (*cbuf)[NHEAD][16][64] = (float(*)[NHEAD][16][64])smem_f;  // [2 slots][head][row][o]
  const int slot = jq >> 1;
  if ((jq & 1) == 0) {
#pragma unroll
    for (int nt = 0; nt < 4; ++nt)
#pragma unroll
      for (int e = 0; e < 4; ++e)
        cbuf[slot][head][q * 4 + e][nt * 16 + l15] = acc[nt][e];
  }
  __syncthreads();
  if ((jq & 1) == 1) {
#pragma unroll
    for (int nt = 0; nt < 4; ++nt)
#pragma unroll
      for (int e = 0; e < 4; ++e)
        cbuf[slot][head][q * 4 + e][nt * 16 + l15] += acc[nt][e];
  }
  __syncthreads();
  {
    const int row = threadIdx.x >> 6;        // 0..15
    const int col4 = (threadIdx.x & 63) * 4; // 0..252
    const int he = col4 >> 6;
    const int oc = col4 & 63;
    f32x4 v;
#pragma unroll
    for (int e = 0; e < 4; ++e)
      v[e] = cbuf[0][he][row][oc + e] + cbuf[1][he][row][oc + e];
    *(f32x4*)(out + (size_t)(i0 + row) * (NHEAD * OUTF) + col4) = v;
  }
}

extern "C" void kernel_launch(void* const* d_in, const int* in_sizes, int n_in,
                              void* d_out, int out_size, void* d_ws, size_t ws_size,
                              hipStream_t stream) {
  const float* x = (const float*)d_in[0];
  const int* adj = (const int*)d_in[1];
  const float* W = (const float*)d_in[2];
  const float* a_src = (const float*)d_in[3];
  const float* a_dst = (const float*)d_in[4];

  float* out = (float*)d_out;                        // [6144][256]
  float* attn = out + (size_t)NNODE * NHEAD * OUTF;  // [4][6144][6144]

  unsigned short* x_hi = (unsigned short*)d_ws;
  unsigned short* x_lo = x_hi + (size_t)NNODE * INFEAT;
  unsigned short* wt_hi = x_lo + (size_t)NNODE * INFEAT;
  unsigned short* wt_lo = wt_hi + (size_t)NHEAD * OUTF * INFEAT;
  unsigned short* h_t = wt_lo + (size_t)NHEAD * OUTF * INFEAT;  // [4][64][6144] bf16
  float* srcL = (float*)(h_t + (size_t)NHEAD * OUTF * NNODE);   // [4][6144]
  float* dstL = srcL + NHEAD * NNODE;                           // [4][6144]
  float* maxdL = dstL + NHEAD * NNODE;                          // [4]
  float* ccL = maxdL + 4;                                       // [4][6144]

  k_prep<<<1024, 256, 0, stream>>>(x, W, x_hi, x_lo, wt_hi, wt_lo);
  k_h<<<NNODE / 16, 256, 0, stream>>>(x_hi, x_lo, wt_hi, wt_lo, a_src, a_dst, h_t, srcL, dstL);
  k_maxd<<<NHEAD, 256, 0, stream>>>(dstL, maxdL);
  k_sums<<<NNODE / 4, 256, 0, stream>>>(adj, srcL, dstL, maxdL, ccL);
  k_attn5<<<NNODE / 16, 1024, 0, stream>>>(adj, srcL, ccL, dstL, h_t, out, attn);
}